// Round 1
// baseline (389.917 us; speedup 1.0000x reference)
//
#include <hip/hip_runtime.h>
#include <stdint.h>

typedef unsigned short u16;
typedef unsigned int u32;
typedef __attribute__((ext_vector_type(8))) short bf16x8;
typedef __attribute__((ext_vector_type(4))) float f32x4;

__device__ __forceinline__ u16 f2b(float f) {
    union { float f; u32 u; } t; t.f = f;
    return (u16)((t.u + 0x7FFFu + ((t.u >> 16) & 1u)) >> 16);
}
__device__ __forceinline__ float b2f(u16 h) {
    union { u32 u; float f; } t; t.u = ((u32)h) << 16;
    return t.f;
}

// ---------------- fp32 -> bf16 cast ----------------
__global__ void cast_bf16_kernel(const float* __restrict__ src, u16* __restrict__ dst, int n4) {
    int i = blockIdx.x * blockDim.x + threadIdx.x;
    if (i >= n4) return;
    float4 f = ((const float4*)src)[i];
    u32 lo = (u32)f2b(f.x) | ((u32)f2b(f.y) << 16);
    u32 hi = (u32)f2b(f.z) | ((u32)f2b(f.w) << 16);
    ((uint2*)dst)[i] = make_uint2(lo, hi);
}

// ---------------- GEMM: y = A @ W^T + bias ----------------
// A [M,1024] bf16 row-major, W [N,1024] bf16 row-major (K-contiguous).
// MODE 0: bf16 output scattered to [B,H,T,64]. MODE 1: fp32 output [M,N] linear.
#define GT 128
#define GK 32
#define GLD 40  // padded LDS row stride (elements): bank stride 20 words -> 2-way max

template<int MODE>
__device__ __forceinline__ void gemm_core(
    const u16* __restrict__ A, const u16* __restrict__ W, const float* __restrict__ bias,
    u16* __restrict__ obf, float* __restrict__ ofp)
{
    __shared__ u16 As[GT * GLD];
    __shared__ u16 Bs[GT * GLD];
    const int tid = threadIdx.x;
    const int lane = tid & 63, w = tid >> 6;
    const int wm = w >> 1, wn = w & 1;
    const int l15 = lane & 15, quad = lane >> 4;
    const int M0 = blockIdx.y * GT, N0 = blockIdx.x * GT;

    f32x4 acc[4][4];
#pragma unroll
    for (int i = 0; i < 4; i++)
#pragma unroll
        for (int j = 0; j < 4; j++) acc[i][j] = (f32x4){0.f, 0.f, 0.f, 0.f};

    const int srow = tid >> 1, shalf = tid & 1;  // 2 threads/row, 16 elems each
    const u16* Ag = A + (size_t)(M0 + srow) * 1024 + shalf * 16;
    const u16* Wg = W + (size_t)(N0 + srow) * 1024 + shalf * 16;
    u16* Asw = As + srow * GLD + shalf * 16;
    u16* Bsw = Bs + srow * GLD + shalf * 16;

    for (int k0 = 0; k0 < 1024; k0 += GK) {
        uint4 a0 = *(const uint4*)(Ag + k0);
        uint4 a1 = *(const uint4*)(Ag + k0 + 8);
        uint4 b0 = *(const uint4*)(Wg + k0);
        uint4 b1 = *(const uint4*)(Wg + k0 + 8);
        __syncthreads();
        *(uint4*)(Asw) = a0;
        *(uint4*)(Asw + 8) = a1;
        *(uint4*)(Bsw) = b0;
        *(uint4*)(Bsw + 8) = b1;
        __syncthreads();
        bf16x8 af[4], bf[4];
#pragma unroll
        for (int mi = 0; mi < 4; mi++)
            af[mi] = *(const bf16x8*)(As + (wm * 64 + mi * 16 + l15) * GLD + quad * 8);
#pragma unroll
        for (int ni = 0; ni < 4; ni++)
            bf[ni] = *(const bf16x8*)(Bs + (wn * 64 + ni * 16 + l15) * GLD + quad * 8);
#pragma unroll
        for (int mi = 0; mi < 4; mi++)
#pragma unroll
            for (int ni = 0; ni < 4; ni++)
                acc[mi][ni] = __builtin_amdgcn_mfma_f32_16x16x32_bf16(af[mi], bf[ni], acc[mi][ni], 0, 0, 0);
    }

#pragma unroll
    for (int mi = 0; mi < 4; mi++)
#pragma unroll
        for (int ni = 0; ni < 4; ni++) {
            int n = N0 + wn * 64 + ni * 16 + l15;
            float bias_n = bias[n];
#pragma unroll
            for (int r = 0; r < 4; r++) {
                int m = M0 + wm * 64 + mi * 16 + quad * 4 + r;  // C-layout: row=quad*4+reg
                float val = acc[mi][ni][r] + bias_n;
                if (MODE == 0) {
                    int b = m >> 11, t = m & 2047;
                    int h = n >> 6, hd = n & 63;
                    obf[((size_t)((b * 16 + h) * 2048 + t) << 6) + hd] = f2b(val);
                } else {
                    ofp[(size_t)m * 1024 + n] = val;
                }
            }
        }
}

__global__ __launch_bounds__(256) void gemm_qkv_kernel(
    const u16* __restrict__ xb,
    const u16* __restrict__ Wq, const u16* __restrict__ Wk, const u16* __restrict__ Wv,
    const float* __restrict__ bq, const float* __restrict__ bk, const float* __restrict__ bv,
    u16* __restrict__ q, u16* __restrict__ k, u16* __restrict__ v)
{
    const u16* W; const float* bias; u16* o;
    if (blockIdx.z == 0)      { W = Wq; bias = bq; o = q; }
    else if (blockIdx.z == 1) { W = Wk; bias = bk; o = k; }
    else                      { W = Wv; bias = bv; o = v; }
    gemm_core<0>(xb, W, bias, o, nullptr);
}

__global__ __launch_bounds__(256) void gemm_out_kernel(
    const u16* __restrict__ ao, const u16* __restrict__ Wo, const float* __restrict__ bo,
    float* __restrict__ out)
{
    gemm_core<1>(ao, Wo, bo, nullptr, out);
}

// ---------------- build extended q/k rows (96 dims) ----------------
// qe[row, 0:64]=q, [64:67]=q@Wqs.T+bqs, [67:96]=0
// ke[row, 0:64]=k, [64:67]=cross(k3,v3), [67:96]=0
__global__ void build_ext_kernel(
    const u16* __restrict__ q, const u16* __restrict__ k, const u16* __restrict__ v,
    const float* __restrict__ Wqs, const float* __restrict__ bqs,
    const float* __restrict__ Wks, const float* __restrict__ bks,
    const float* __restrict__ Wvs, const float* __restrict__ bvs,
    u16* __restrict__ qe, u16* __restrict__ ke)
{
    int row = blockIdx.x * blockDim.x + threadIdx.x;
    if (row >= 2 * 16 * 2048) return;
    const u16* qr = q + (size_t)row * 64;
    const u16* kr = k + (size_t)row * 64;
    const u16* vr = v + (size_t)row * 64;

    float qs0 = bqs[0], qs1 = bqs[1], qs2 = bqs[2];
    float ks0 = bks[0], ks1 = bks[1], ks2 = bks[2];
    float vs0 = bvs[0], vs1 = bvs[1], vs2 = bvs[2];
#pragma unroll
    for (int j = 0; j < 64; j += 8) {
        bf16x8 qv = *(const bf16x8*)(qr + j);
        bf16x8 kv = *(const bf16x8*)(kr + j);
        bf16x8 vv = *(const bf16x8*)(vr + j);
#pragma unroll
        for (int i = 0; i < 8; i++) {
            float qf = b2f((u16)qv[i]);
            float kf = b2f((u16)kv[i]);
            float vf = b2f((u16)vv[i]);
            qs0 += qf * Wqs[j + i]; qs1 += qf * Wqs[64 + j + i]; qs2 += qf * Wqs[128 + j + i];
            ks0 += kf * Wks[j + i]; ks1 += kf * Wks[64 + j + i]; ks2 += kf * Wks[128 + j + i];
            vs0 += vf * Wvs[j + i]; vs1 += vf * Wvs[64 + j + i]; vs2 += vf * Wvs[128 + j + i];
        }
    }
    float c0 = ks1 * vs2 - ks2 * vs1;
    float c1 = ks2 * vs0 - ks0 * vs2;
    float c2 = ks0 * vs1 - ks1 * vs0;

    u16* qer = qe + (size_t)row * 96;
    u16* ker = ke + (size_t)row * 96;
#pragma unroll
    for (int j = 0; j < 64; j += 8) {
        *(bf16x8*)(qer + j) = *(const bf16x8*)(qr + j);
        *(bf16x8*)(ker + j) = *(const bf16x8*)(kr + j);
    }
    *(uint2*)(qer + 64) = make_uint2((u32)f2b(qs0) | ((u32)f2b(qs1) << 16), (u32)f2b(qs2));
    *(uint2*)(ker + 64) = make_uint2((u32)f2b(c0) | ((u32)f2b(c1) << 16), (u32)f2b(c2));
    uint2 z = make_uint2(0u, 0u);
#pragma unroll
    for (int j = 68; j < 96; j += 4) {
        *(uint2*)(qer + j) = z;
        *(uint2*)(ker + j) = z;
    }
}

// ---------------- flash attention over extended dim 96 ----------------
#define LKS 104  // Ks row stride (elems): 52 words -> 2-way
#define LVT 72   // Vt row stride: 36 words -> 2-way
#define LPS 72   // P  row stride: 36 words -> 2-way

__global__ __launch_bounds__(256) void attn_kernel(
    const u16* __restrict__ qe, const u16* __restrict__ ke, const u16* __restrict__ v,
    const float* __restrict__ temp_p, u16* __restrict__ out)
{
    __shared__ u16 Ks[64 * LKS];
    __shared__ u16 Vt[64 * LVT];
    __shared__ u16 Ps[4 * 16 * LPS];

    const int tid = threadIdx.x;
    const int lane = tid & 63, w = tid >> 6;
    const int l15 = lane & 15, quad = lane >> 4;
    const int bh = blockIdx.y;
    const int q0 = blockIdx.x * 64;
    const float temp = *temp_p;

    const u16* qeb = qe + (size_t)bh * 2048 * 96;
    const u16* keb = ke + (size_t)bh * 2048 * 96;
    const u16* vbp = v + (size_t)bh * 2048 * 64;

    // Q fragments (A-layout): row = q0 + w*16 + l15, k = ks*32 + quad*8 + j
    bf16x8 aq[3];
    {
        const u16* qrow = qeb + (size_t)(q0 + w * 16 + l15) * 96;
#pragma unroll
        for (int ks = 0; ks < 3; ks++) aq[ks] = *(const bf16x8*)(qrow + ks * 32 + quad * 8);
    }

    f32x4 O[4];
#pragma unroll
    for (int i = 0; i < 4; i++) O[i] = (f32x4){0.f, 0.f, 0.f, 0.f};
    float m_i[4], l_i[4];
#pragma unroll
    for (int r = 0; r < 4; r++) { m_i[r] = -1e30f; l_i[r] = 0.f; }

    const int krow = tid >> 2, kpart = tid & 3;       // Ks staging
    const int vrow = tid >> 3, vcol = (tid & 7) * 8;  // V staging (transpose)
    u16* pw = Ps + w * 16 * LPS;

    for (int kb = 0; kb < 2048; kb += 64) {
        const u16* kg = keb + (size_t)(kb + krow) * 96 + kpart * 24;
        uint4 kx0 = *(const uint4*)(kg);
        uint4 kx1 = *(const uint4*)(kg + 8);
        uint4 kx2 = *(const uint4*)(kg + 16);
        uint4 vx0 = *(const uint4*)(vbp + (size_t)(kb + vrow) * 64 + vcol);
        uint4 vx1 = *(const uint4*)(vbp + (size_t)(kb + vrow + 32) * 64 + vcol);
        __syncthreads();  // previous iter's LDS reads done
        *(uint4*)(Ks + krow * LKS + kpart * 24) = kx0;
        *(uint4*)(Ks + krow * LKS + kpart * 24 + 8) = kx1;
        *(uint4*)(Ks + krow * LKS + kpart * 24 + 16) = kx2;
        {
            const u16* p0 = (const u16*)&vx0;
            const u16* p1 = (const u16*)&vx1;
#pragma unroll
            for (int j = 0; j < 8; j++) {
                Vt[(vcol + j) * LVT + vrow] = p0[j];
                Vt[(vcol + j) * LVT + vrow + 32] = p1[j];
            }
        }
        __syncthreads();

        // S = Qe * Ke^T  (16 q-rows x 64 k-cols per wave), K-dim 96
        f32x4 S[4];
#pragma unroll
        for (int nt = 0; nt < 4; nt++) S[nt] = (f32x4){0.f, 0.f, 0.f, 0.f};
#pragma unroll
        for (int nt = 0; nt < 4; nt++)
#pragma unroll
            for (int ks = 0; ks < 3; ks++) {
                bf16x8 bk_ = *(const bf16x8*)(Ks + (nt * 16 + l15) * LKS + ks * 32 + quad * 8);
                S[nt] = __builtin_amdgcn_mfma_f32_16x16x32_bf16(aq[ks], bk_, S[nt], 0, 0, 0);
            }

        float rmax[4], rsum[4], mnew[4], alpha[4];
#pragma unroll
        for (int nt = 0; nt < 4; nt++)
#pragma unroll
            for (int r = 0; r < 4; r++) S[nt][r] *= temp;
#pragma unroll
        for (int r = 0; r < 4; r++)
            rmax[r] = fmaxf(fmaxf(S[0][r], S[1][r]), fmaxf(S[2][r], S[3][r]));
#pragma unroll
        for (int off = 1; off < 16; off <<= 1)
#pragma unroll
            for (int r = 0; r < 4; r++)
                rmax[r] = fmaxf(rmax[r], __shfl_xor(rmax[r], off));
#pragma unroll
        for (int r = 0; r < 4; r++) {
            mnew[r] = fmaxf(m_i[r], rmax[r]);
            alpha[r] = __expf(m_i[r] - mnew[r]);
            rsum[r] = 0.f;
        }
#pragma unroll
        for (int nt = 0; nt < 4; nt++)
#pragma unroll
            for (int r = 0; r < 4; r++) {
                float p = __expf(S[nt][r] - mnew[r]);
                S[nt][r] = p;
                rsum[r] += p;
            }
#pragma unroll
        for (int off = 1; off < 16; off <<= 1)
#pragma unroll
            for (int r = 0; r < 4; r++)
                rsum[r] += __shfl_xor(rsum[r], off);
#pragma unroll
        for (int r = 0; r < 4; r++) {
            l_i[r] = l_i[r] * alpha[r] + rsum[r];
            m_i[r] = mnew[r];
        }
#pragma unroll
        for (int nt = 0; nt < 4; nt++)
#pragma unroll
            for (int r = 0; r < 4; r++) O[nt][r] *= alpha[r];

        // P (C-layout) -> per-wave LDS -> A-layout frags; in-wave DS ordering suffices
#pragma unroll
        for (int nt = 0; nt < 4; nt++)
#pragma unroll
            for (int r = 0; r < 4; r++)
                pw[(quad * 4 + r) * LPS + nt * 16 + l15] = f2b(S[nt][r]);
#pragma unroll
        for (int nt = 0; nt < 4; nt++)
#pragma unroll
            for (int kk = 0; kk < 2; kk++) {
                bf16x8 pa = *(const bf16x8*)(pw + l15 * LPS + kk * 32 + quad * 8);
                bf16x8 vf = *(const bf16x8*)(Vt + (nt * 16 + l15) * LVT + kk * 32 + quad * 8);
                O[nt] = __builtin_amdgcn_mfma_f32_16x16x32_bf16(pa, vf, O[nt], 0, 0, 0);
            }
    }

    // epilogue: write [B,T,D] bf16
    const int b = bh >> 4, h = bh & 15;
#pragma unroll
    for (int nt = 0; nt < 4; nt++)
#pragma unroll
        for (int r = 0; r < 4; r++) {
            int tq = q0 + w * 16 + quad * 4 + r;
            int d = h * 64 + nt * 16 + l15;
            out[(size_t)(b * 2048 + tq) * 1024 + d] = f2b(O[nt][r] / l_i[r]);
        }
}

// ---------------- launch ----------------
extern "C" void kernel_launch(void* const* d_in, const int* in_sizes, int n_in,
                              void* d_out, int out_size, void* d_ws, size_t ws_size,
                              hipStream_t stream)
{
    (void)in_sizes; (void)n_in; (void)out_size; (void)ws_size;
    const float* x   = (const float*)d_in[0];
    const float* Wq  = (const float*)d_in[1];
    const float* bq  = (const float*)d_in[2];
    const float* Wk  = (const float*)d_in[3];
    const float* bk  = (const float*)d_in[4];
    const float* Wv  = (const float*)d_in[5];
    const float* bv  = (const float*)d_in[6];
    const float* Wo  = (const float*)d_in[7];
    const float* bo  = (const float*)d_in[8];
    const float* Wqs = (const float*)d_in[9];
    const float* bqs = (const float*)d_in[10];
    const float* Wks = (const float*)d_in[11];
    const float* bks = (const float*)d_in[12];
    const float* Wvs = (const float*)d_in[13];
    const float* bvs = (const float*)d_in[14];
    const float* temp = (const float*)d_in[15];

    char* ws = (char*)d_ws;
    u16* xb  = (u16*)(ws);                 // 8 MB
    u16* Wqb = (u16*)(ws + 8388608);       // 2 MB
    u16* Wkb = (u16*)(ws + 10485760);      // 2 MB
    u16* Wvb = (u16*)(ws + 12582912);      // 2 MB
    u16* Wob = (u16*)(ws + 14680064);      // 2 MB
    u16* qb  = (u16*)(ws + 16777216);      // 8 MB  [B,H,T,64]
    u16* kbq = (u16*)(ws + 25165824);      // 8 MB
    u16* vbq = (u16*)(ws + 33554432);      // 8 MB
    u16* qeb = (u16*)(ws + 41943040);      // 12 MB [B,H,T,96]
    u16* keb = (u16*)(ws + 54525952);      // 12 MB
    u16* aob = (u16*)(ws + 67108864);      // 8 MB  [B,T,D]

    cast_bf16_kernel<<<4096, 256, 0, stream>>>(x, xb, 1048576);
    cast_bf16_kernel<<<1024, 256, 0, stream>>>(Wq, Wqb, 262144);
    cast_bf16_kernel<<<1024, 256, 0, stream>>>(Wk, Wkb, 262144);
    cast_bf16_kernel<<<1024, 256, 0, stream>>>(Wv, Wvb, 262144);
    cast_bf16_kernel<<<1024, 256, 0, stream>>>(Wo, Wob, 262144);

    gemm_qkv_kernel<<<dim3(8, 32, 3), 256, 0, stream>>>(xb, Wqb, Wkb, Wvb, bq, bk, bv, qb, kbq, vbq);
    build_ext_kernel<<<256, 256, 0, stream>>>(qb, kbq, vbq, Wqs, bqs, Wks, bks, Wvs, bvs, qeb, keb);
    attn_kernel<<<dim3(32, 32), 256, 0, stream>>>(qeb, keb, vbq, temp, aob);
    gemm_out_kernel<<<dim3(8, 32), 256, 0, stream>>>(aob, Wob, bo, (float*)d_out);
}

// Round 2
// 347.048 us; speedup vs baseline: 1.1235x; 1.1235x over previous
//
#include <hip/hip_runtime.h>
#include <stdint.h>

typedef unsigned short u16;
typedef unsigned int u32;
typedef __attribute__((ext_vector_type(8))) short bf16x8;
typedef __attribute__((ext_vector_type(4))) float f32x4;

__device__ __forceinline__ u16 f2b(float f) {
    union { float f; u32 u; } t; t.f = f;
    return (u16)((t.u + 0x7FFFu + ((t.u >> 16) & 1u)) >> 16);
}
__device__ __forceinline__ float b2f(u16 h) {
    union { u32 u; float f; } t; t.u = ((u32)h) << 16;
    return t.f;
}

// ---------------- fp32 -> bf16 cast ----------------
__global__ void cast_bf16_kernel(const float* __restrict__ src, u16* __restrict__ dst, int n4) {
    int i = blockIdx.x * blockDim.x + threadIdx.x;
    if (i >= n4) return;
    float4 f = ((const float4*)src)[i];
    u32 lo = (u32)f2b(f.x) | ((u32)f2b(f.y) << 16);
    u32 hi = (u32)f2b(f.z) | ((u32)f2b(f.w) << 16);
    ((uint2*)dst)[i] = make_uint2(lo, hi);
}

// ---------------- GEMM: y = A @ W^T + bias (unchanged this round) ----------------
#define GT 128
#define GK 32
#define GLD 40

template<int MODE>
__device__ __forceinline__ void gemm_core(
    const u16* __restrict__ A, const u16* __restrict__ W, const float* __restrict__ bias,
    u16* __restrict__ obf, float* __restrict__ ofp)
{
    __shared__ u16 As[GT * GLD];
    __shared__ u16 Bs[GT * GLD];
    const int tid = threadIdx.x;
    const int lane = tid & 63, w = tid >> 6;
    const int wm = w >> 1, wn = w & 1;
    const int l15 = lane & 15, quad = lane >> 4;
    const int M0 = blockIdx.y * GT, N0 = blockIdx.x * GT;

    f32x4 acc[4][4];
#pragma unroll
    for (int i = 0; i < 4; i++)
#pragma unroll
        for (int j = 0; j < 4; j++) acc[i][j] = (f32x4){0.f, 0.f, 0.f, 0.f};

    const int srow = tid >> 1, shalf = tid & 1;
    const u16* Ag = A + (size_t)(M0 + srow) * 1024 + shalf * 16;
    const u16* Wg = W + (size_t)(N0 + srow) * 1024 + shalf * 16;
    u16* Asw = As + srow * GLD + shalf * 16;
    u16* Bsw = Bs + srow * GLD + shalf * 16;

    for (int k0 = 0; k0 < 1024; k0 += GK) {
        uint4 a0 = *(const uint4*)(Ag + k0);
        uint4 a1 = *(const uint4*)(Ag + k0 + 8);
        uint4 b0 = *(const uint4*)(Wg + k0);
        uint4 b1 = *(const uint4*)(Wg + k0 + 8);
        __syncthreads();
        *(uint4*)(Asw) = a0;
        *(uint4*)(Asw + 8) = a1;
        *(uint4*)(Bsw) = b0;
        *(uint4*)(Bsw + 8) = b1;
        __syncthreads();
        bf16x8 af[4], bf[4];
#pragma unroll
        for (int mi = 0; mi < 4; mi++)
            af[mi] = *(const bf16x8*)(As + (wm * 64 + mi * 16 + l15) * GLD + quad * 8);
#pragma unroll
        for (int ni = 0; ni < 4; ni++)
            bf[ni] = *(const bf16x8*)(Bs + (wn * 64 + ni * 16 + l15) * GLD + quad * 8);
#pragma unroll
        for (int mi = 0; mi < 4; mi++)
#pragma unroll
            for (int ni = 0; ni < 4; ni++)
                acc[mi][ni] = __builtin_amdgcn_mfma_f32_16x16x32_bf16(af[mi], bf[ni], acc[mi][ni], 0, 0, 0);
    }

#pragma unroll
    for (int mi = 0; mi < 4; mi++)
#pragma unroll
        for (int ni = 0; ni < 4; ni++) {
            int n = N0 + wn * 64 + ni * 16 + l15;
            float bias_n = bias[n];
#pragma unroll
            for (int r = 0; r < 4; r++) {
                int m = M0 + wm * 64 + mi * 16 + quad * 4 + r;
                float val = acc[mi][ni][r] + bias_n;
                if (MODE == 0) {
                    int b = m >> 11, t = m & 2047;
                    int h = n >> 6, hd = n & 63;
                    obf[((size_t)((b * 16 + h) * 2048 + t) << 6) + hd] = f2b(val);
                } else {
                    ofp[(size_t)m * 1024 + n] = val;
                }
            }
        }
}

__global__ __launch_bounds__(256) void gemm_qkv_kernel(
    const u16* __restrict__ xb,
    const u16* __restrict__ Wq, const u16* __restrict__ Wk, const u16* __restrict__ Wv,
    const float* __restrict__ bq, const float* __restrict__ bk, const float* __restrict__ bv,
    u16* __restrict__ q, u16* __restrict__ k, u16* __restrict__ v)
{
    const u16* W; const float* bias; u16* o;
    if (blockIdx.z == 0)      { W = Wq; bias = bq; o = q; }
    else if (blockIdx.z == 1) { W = Wk; bias = bk; o = k; }
    else                      { W = Wv; bias = bv; o = v; }
    gemm_core<0>(xb, W, bias, o, nullptr);
}

__global__ __launch_bounds__(256) void gemm_out_kernel(
    const u16* __restrict__ ao, const u16* __restrict__ Wo, const float* __restrict__ bo,
    float* __restrict__ out)
{
    gemm_core<1>(ao, Wo, bo, nullptr, out);
}

// ---------------- build extended q/k rows (96 dims), temp folded into qe ----------------
__global__ void build_ext_kernel(
    const u16* __restrict__ q, const u16* __restrict__ k, const u16* __restrict__ v,
    const float* __restrict__ Wqs, const float* __restrict__ bqs,
    const float* __restrict__ Wks, const float* __restrict__ bks,
    const float* __restrict__ Wvs, const float* __restrict__ bvs,
    const float* __restrict__ temp_p,
    u16* __restrict__ qe, u16* __restrict__ ke)
{
    int row = blockIdx.x * blockDim.x + threadIdx.x;
    if (row >= 2 * 16 * 2048) return;
    const float temp = *temp_p;
    const u16* qr = q + (size_t)row * 64;
    const u16* kr = k + (size_t)row * 64;
    const u16* vr = v + (size_t)row * 64;

    float qs0 = bqs[0], qs1 = bqs[1], qs2 = bqs[2];
    float ks0 = bks[0], ks1 = bks[1], ks2 = bks[2];
    float vs0 = bvs[0], vs1 = bvs[1], vs2 = bvs[2];
#pragma unroll
    for (int j = 0; j < 64; j += 8) {
        bf16x8 qv = *(const bf16x8*)(qr + j);
        bf16x8 kv = *(const bf16x8*)(kr + j);
        bf16x8 vv = *(const bf16x8*)(vr + j);
#pragma unroll
        for (int i = 0; i < 8; i++) {
            float qf = b2f((u16)qv[i]);
            float kf = b2f((u16)kv[i]);
            float vf = b2f((u16)vv[i]);
            qs0 += qf * Wqs[j + i]; qs1 += qf * Wqs[64 + j + i]; qs2 += qf * Wqs[128 + j + i];
            ks0 += kf * Wks[j + i]; ks1 += kf * Wks[64 + j + i]; ks2 += kf * Wks[128 + j + i];
            vs0 += vf * Wvs[j + i]; vs1 += vf * Wvs[64 + j + i]; vs2 += vf * Wvs[128 + j + i];
        }
    }
    float c0 = ks1 * vs2 - ks2 * vs1;
    float c1 = ks2 * vs0 - ks0 * vs2;
    float c2 = ks0 * vs1 - ks1 * vs0;

    u16* qer = qe + (size_t)row * 96;
    u16* ker = ke + (size_t)row * 96;
#pragma unroll
    for (int j = 0; j < 64; j += 8) {
        bf16x8 qv = *(const bf16x8*)(qr + j);
        bf16x8 sq;
#pragma unroll
        for (int i = 0; i < 8; i++) sq[i] = (short)f2b(b2f((u16)qv[i]) * temp);
        *(bf16x8*)(qer + j) = sq;
        *(bf16x8*)(ker + j) = *(const bf16x8*)(kr + j);
    }
    *(uint2*)(qer + 64) = make_uint2((u32)f2b(qs0 * temp) | ((u32)f2b(qs1 * temp) << 16), (u32)f2b(qs2 * temp));
    *(uint2*)(ker + 64) = make_uint2((u32)f2b(c0) | ((u32)f2b(c1) << 16), (u32)f2b(c2));
    uint2 z = make_uint2(0u, 0u);
#pragma unroll
    for (int j = 68; j < 96; j += 4) {
        *(uint2*)(qer + j) = z;
        *(uint2*)(ker + j) = z;
    }
}

// ---------------- flash attention, conflict-free odd-word LDS strides ----------------
// word strides: LKS/2=49, LVT/2=33, LPS/2=33 -- all odd -> <=2-way bank aliasing (free)
#define LKS 98
#define LVT 66
#define LPS 66

__device__ __forceinline__ bf16x8 lds_frag32(const u32* __restrict__ p, int wbase) {
    union { u32 u[4]; bf16x8 v; } t;
    t.u[0] = p[wbase]; t.u[1] = p[wbase + 1]; t.u[2] = p[wbase + 2]; t.u[3] = p[wbase + 3];
    return t.v;
}

__global__ __launch_bounds__(256) void attn_kernel(
    const u16* __restrict__ qe, const u16* __restrict__ ke, const u16* __restrict__ v,
    u16* __restrict__ out)
{
    __shared__ u16 Ks[64 * LKS];   // [key 0..63][dim 0..95]
    __shared__ u16 Vt[64 * LVT];   // [hd 0..63][key 0..63]
    __shared__ u16 Ps[8 * 16 * LPS]; // per (wave,subtile): 16 q-rows x 64 keys

    const int tid = threadIdx.x;
    const int lane = tid & 63, w = tid >> 6;
    const int l15 = lane & 15, quad = lane >> 4;
    const int bh = blockIdx.y;
    const int q0 = blockIdx.x * 128;

    const u16* qeb = qe + (size_t)bh * 2048 * 96;
    const u16* keb = ke + (size_t)bh * 2048 * 96;
    const u16* vbp = v + (size_t)bh * 2048 * 64;

    u32* ks32 = (u32*)Ks;
    const u32* vt32 = (const u32*)Vt;
    const u32* ps32 = (const u32*)Ps;

    // Q fragments, 2 subtiles per wave (rows q0 + w*32 + s*16 + l15), temp pre-folded
    bf16x8 aq[2][3];
#pragma unroll
    for (int s = 0; s < 2; s++) {
        const u16* qrow = qeb + (size_t)(q0 + w * 32 + s * 16 + l15) * 96;
#pragma unroll
        for (int ks = 0; ks < 3; ks++) aq[s][ks] = *(const bf16x8*)(qrow + ks * 32 + quad * 8);
    }

    // constant ones B-frag: B[k][n] = (n==0)
    bf16x8 ones;
#pragma unroll
    for (int i = 0; i < 8; i++) ones[i] = (l15 == 0) ? (short)0x3F80 : (short)0;

    f32x4 O[2][4], Lx[2];
    float m_i[2][4];
#pragma unroll
    for (int s = 0; s < 2; s++) {
        Lx[s] = (f32x4){0.f, 0.f, 0.f, 0.f};
#pragma unroll
        for (int nt = 0; nt < 4; nt++) O[s][nt] = (f32x4){0.f, 0.f, 0.f, 0.f};
#pragma unroll
        for (int r = 0; r < 4; r++) m_i[s][r] = -1e30f;
    }

    const int krow = tid >> 2, kpart = tid & 3;       // K staging: 4 thr/row, 3 x 16B each
    const int vrow8 = tid >> 3, vcol8 = (tid & 7) * 8; // V staging (transpose)

    for (int kb = 0; kb < 2048; kb += 64) {
        const u16* kg = keb + (size_t)(kb + krow) * 96;
        uint4 kx0 = *(const uint4*)(kg + kpart * 8);
        uint4 kx1 = *(const uint4*)(kg + (kpart + 4) * 8);
        uint4 kx2 = *(const uint4*)(kg + (kpart + 8) * 8);
        uint4 vx0 = *(const uint4*)(vbp + (size_t)(kb + vrow8) * 64 + vcol8);
        uint4 vx1 = *(const uint4*)(vbp + (size_t)(kb + vrow8 + 32) * 64 + vcol8);
        __syncthreads();
        {
            int base = krow * 49;
            int c0 = base + kpart * 4, c1 = base + (kpart + 4) * 4, c2 = base + (kpart + 8) * 4;
            ks32[c0] = kx0.x; ks32[c0 + 1] = kx0.y; ks32[c0 + 2] = kx0.z; ks32[c0 + 3] = kx0.w;
            ks32[c1] = kx1.x; ks32[c1 + 1] = kx1.y; ks32[c1 + 2] = kx1.z; ks32[c1 + 3] = kx1.w;
            ks32[c2] = kx2.x; ks32[c2 + 1] = kx2.y; ks32[c2 + 2] = kx2.z; ks32[c2 + 3] = kx2.w;
        }
        {
            const u16* p0 = (const u16*)&vx0;
            const u16* p1 = (const u16*)&vx1;
#pragma unroll
            for (int j = 0; j < 8; j++) {
                Vt[(vcol8 + j) * LVT + vrow8] = p0[j];
                Vt[(vcol8 + j) * LVT + vrow8 + 32] = p1[j];
            }
        }
        __syncthreads();

        // ---- S = Qe * Ke^T for both subtiles (K-frags read once) ----
        f32x4 S[2][4];
#pragma unroll
        for (int s = 0; s < 2; s++)
#pragma unroll
            for (int nt = 0; nt < 4; nt++) S[s][nt] = (f32x4){0.f, 0.f, 0.f, 0.f};
#pragma unroll
        for (int ks = 0; ks < 3; ks++) {
            bf16x8 bk[4];
#pragma unroll
            for (int nt = 0; nt < 4; nt++)
                bk[nt] = lds_frag32(ks32, (nt * 16 + l15) * 49 + ks * 16 + quad * 4);
#pragma unroll
            for (int s = 0; s < 2; s++)
#pragma unroll
                for (int nt = 0; nt < 4; nt++)
                    S[s][nt] = __builtin_amdgcn_mfma_f32_16x16x32_bf16(aq[s][ks], bk[nt], S[s][nt], 0, 0, 0);
        }

        // ---- online softmax (both subtiles interleaved for shfl ILP) ----
        float rmax[2][4], alpha[2][4];
#pragma unroll
        for (int s = 0; s < 2; s++)
#pragma unroll
            for (int r = 0; r < 4; r++)
                rmax[s][r] = fmaxf(fmaxf(S[s][0][r], S[s][1][r]), fmaxf(S[s][2][r], S[s][3][r]));
#pragma unroll
        for (int off = 1; off < 16; off <<= 1)
#pragma unroll
            for (int s = 0; s < 2; s++)
#pragma unroll
                for (int r = 0; r < 4; r++)
                    rmax[s][r] = fmaxf(rmax[s][r], __shfl_xor(rmax[s][r], off));
#pragma unroll
        for (int s = 0; s < 2; s++)
#pragma unroll
            for (int r = 0; r < 4; r++) {
                float mnew = fmaxf(m_i[s][r], rmax[s][r]);
                alpha[s][r] = __expf(m_i[s][r] - mnew);
                m_i[s][r] = mnew;
            }
#pragma unroll
        for (int s = 0; s < 2; s++) {
#pragma unroll
            for (int nt = 0; nt < 4; nt++)
#pragma unroll
                for (int r = 0; r < 4; r++)
                    S[s][nt][r] = __expf(S[s][nt][r] - m_i[s][r]);
#pragma unroll
            for (int nt = 0; nt < 4; nt++)
#pragma unroll
                for (int r = 0; r < 4; r++) O[s][nt][r] *= alpha[s][r];
#pragma unroll
            for (int r = 0; r < 4; r++) Lx[s][r] *= alpha[s][r];
            // P -> per-(wave,subtile) LDS region (in-wave DS ordering suffices)
            u16* pw = Ps + (w * 2 + s) * 16 * LPS;
#pragma unroll
            for (int nt = 0; nt < 4; nt++)
#pragma unroll
                for (int r = 0; r < 4; r++)
                    pw[(quad * 4 + r) * LPS + nt * 16 + l15] = f2b(S[s][nt][r]);
        }

        // ---- O += P * V ; L += P * ones ----
#pragma unroll
        for (int kk = 0; kk < 2; kk++) {
            bf16x8 vf[4];
#pragma unroll
            for (int nt = 0; nt < 4; nt++)
                vf[nt] = lds_frag32(vt32, (nt * 16 + l15) * 33 + kk * 16 + quad * 4);
#pragma unroll
            for (int s = 0; s < 2; s++) {
                bf16x8 pa = lds_frag32(ps32, ((w * 2 + s) * 16 + l15) * 33 + kk * 16 + quad * 4);
#pragma unroll
                for (int nt = 0; nt < 4; nt++)
                    O[s][nt] = __builtin_amdgcn_mfma_f32_16x16x32_bf16(pa, vf[nt], O[s][nt], 0, 0, 0);
                Lx[s] = __builtin_amdgcn_mfma_f32_16x16x32_bf16(pa, ones, Lx[s], 0, 0, 0);
            }
        }
    }

    // ---- epilogue: out[b][t][h*64+d] = O / l ----
    const int b = bh >> 4, h = bh & 15;
#pragma unroll
    for (int s = 0; s < 2; s++) {
        float linv[4];
#pragma unroll
        for (int r = 0; r < 4; r++)
            linv[r] = 1.0f / __shfl(Lx[s][r], lane & 48);
#pragma unroll
        for (int nt = 0; nt < 4; nt++)
#pragma unroll
            for (int r = 0; r < 4; r++) {
                int tq = q0 + w * 32 + s * 16 + quad * 4 + r;
                int d = h * 64 + nt * 16 + l15;
                out[(size_t)(b * 2048 + tq) * 1024 + d] = f2b(O[s][nt][r] * linv[r]);
            }
    }
}

// ---------------- launch ----------------
extern "C" void kernel_launch(void* const* d_in, const int* in_sizes, int n_in,
                              void* d_out, int out_size, void* d_ws, size_t ws_size,
                              hipStream_t stream)
{
    (void)in_sizes; (void)n_in; (void)out_size; (void)ws_size;
    const float* x   = (const float*)d_in[0];
    const float* Wq  = (const float*)d_in[1];
    const float* bq  = (const float*)d_in[2];
    const float* Wk  = (const float*)d_in[3];
    const float* bk  = (const float*)d_in[4];
    const float* Wv  = (const float*)d_in[5];
    const float* bv  = (const float*)d_in[6];
    const float* Wo  = (const float*)d_in[7];
    const float* bo  = (const float*)d_in[8];
    const float* Wqs = (const float*)d_in[9];
    const float* bqs = (const float*)d_in[10];
    const float* Wks = (const float*)d_in[11];
    const float* bks = (const float*)d_in[12];
    const float* Wvs = (const float*)d_in[13];
    const float* bvs = (const float*)d_in[14];
    const float* temp = (const float*)d_in[15];

    char* ws = (char*)d_ws;
    u16* xb  = (u16*)(ws);                 // 8 MB
    u16* Wqb = (u16*)(ws + 8388608);       // 2 MB
    u16* Wkb = (u16*)(ws + 10485760);      // 2 MB
    u16* Wvb = (u16*)(ws + 12582912);      // 2 MB
    u16* Wob = (u16*)(ws + 14680064);      // 2 MB
    u16* qb  = (u16*)(ws + 16777216);      // 8 MB  [B,H,T,64]
    u16* kbq = (u16*)(ws + 25165824);      // 8 MB
    u16* vbq = (u16*)(ws + 33554432);      // 8 MB
    u16* qeb = (u16*)(ws + 41943040);      // 12 MB [B,H,T,96]
    u16* keb = (u16*)(ws + 54525952);      // 12 MB
    u16* aob = (u16*)(ws + 67108864);      // 8 MB  [B,T,D]

    cast_bf16_kernel<<<4096, 256, 0, stream>>>(x, xb, 1048576);
    cast_bf16_kernel<<<1024, 256, 0, stream>>>(Wq, Wqb, 262144);
    cast_bf16_kernel<<<1024, 256, 0, stream>>>(Wk, Wkb, 262144);
    cast_bf16_kernel<<<1024, 256, 0, stream>>>(Wv, Wvb, 262144);
    cast_bf16_kernel<<<1024, 256, 0, stream>>>(Wo, Wob, 262144);

    gemm_qkv_kernel<<<dim3(8, 32, 3), 256, 0, stream>>>(xb, Wqb, Wkb, Wvb, bq, bk, bv, qb, kbq, vbq);
    build_ext_kernel<<<256, 256, 0, stream>>>(qb, kbq, vbq, Wqs, bqs, Wks, bks, Wvs, bvs, temp, qeb, keb);
    attn_kernel<<<dim3(16, 32), 256, 0, stream>>>(qeb, keb, vbq, aob);
    gemm_out_kernel<<<dim3(8, 32), 256, 0, stream>>>(aob, Wob, bo, (float*)d_out);
}

// Round 3
// 299.154 us; speedup vs baseline: 1.3034x; 1.1601x over previous
//
#include <hip/hip_runtime.h>
#include <stdint.h>

typedef unsigned short u16;
typedef unsigned int u32;
typedef __attribute__((ext_vector_type(8))) short bf16x8;
typedef __attribute__((ext_vector_type(4))) float f32x4;

__device__ __forceinline__ u16 f2b(float f) {
    union { float f; u32 u; } t; t.f = f;
    return (u16)((t.u + 0x7FFFu + ((t.u >> 16) & 1u)) >> 16);
}
__device__ __forceinline__ float b2f(u16 h) {
    union { u32 u; float f; } t; t.u = ((u32)h) << 16;
    return t.f;
}
__device__ __forceinline__ u32 pack2(float a, float b) {
    return (u32)f2b(a) | ((u32)f2b(b) << 16);
}

// ---------------- fused fp32 -> bf16 cast (x + 4 weights, one launch) ----------------
__global__ void cast_all_kernel(const float* __restrict__ x,
                                const float* __restrict__ Wq, const float* __restrict__ Wk,
                                const float* __restrict__ Wv, const float* __restrict__ Wo,
                                u16* __restrict__ xb, u16* __restrict__ Wqb, u16* __restrict__ Wkb,
                                u16* __restrict__ Wvb, u16* __restrict__ Wob) {
    int i = blockIdx.x * blockDim.x + threadIdx.x;  // float4 index, total 2097152
    const float* s; u16* d; int off;
    if (i < 1048576) { s = x; d = xb; off = i; }
    else {
        int j = i - 1048576;
        int w = j >> 18; off = j & 262143;
        if (w == 0) { s = Wq; d = Wqb; }
        else if (w == 1) { s = Wk; d = Wkb; }
        else if (w == 2) { s = Wv; d = Wvb; }
        else { s = Wo; d = Wob; }
    }
    float4 f = ((const float4*)s)[off];
    ((uint2*)d)[off] = make_uint2(pack2(f.x, f.y), pack2(f.z, f.w));
}

// ---------------- GEMM: y = A @ W^T + bias ----------------
#define GT 128
#define GK 32
#define GLD 40

template<int MODE>
__device__ __forceinline__ void gemm_core(
    const u16* __restrict__ A, const u16* __restrict__ W, const float* __restrict__ bias,
    u16* __restrict__ obf, u16* __restrict__ vtout, float* __restrict__ ofp)
{
    __shared__ u16 As[GT * GLD];
    __shared__ u16 Bs[GT * GLD];
    const int tid = threadIdx.x;
    const int lane = tid & 63, w = tid >> 6;
    const int wm = w >> 1, wn = w & 1;
    const int l15 = lane & 15, quad = lane >> 4;
    const int M0 = blockIdx.y * GT, N0 = blockIdx.x * GT;

    f32x4 acc[4][4];
#pragma unroll
    for (int i = 0; i < 4; i++)
#pragma unroll
        for (int j = 0; j < 4; j++) acc[i][j] = (f32x4){0.f, 0.f, 0.f, 0.f};

    const int srow = tid >> 1, shalf = tid & 1;
    const u16* Ag = A + (size_t)(M0 + srow) * 1024 + shalf * 16;
    const u16* Wg = W + (size_t)(N0 + srow) * 1024 + shalf * 16;
    u16* Asw = As + srow * GLD + shalf * 16;
    u16* Bsw = Bs + srow * GLD + shalf * 16;

    for (int k0 = 0; k0 < 1024; k0 += GK) {
        uint4 a0 = *(const uint4*)(Ag + k0);
        uint4 a1 = *(const uint4*)(Ag + k0 + 8);
        uint4 b0 = *(const uint4*)(Wg + k0);
        uint4 b1 = *(const uint4*)(Wg + k0 + 8);
        __syncthreads();
        *(uint4*)(Asw) = a0;
        *(uint4*)(Asw + 8) = a1;
        *(uint4*)(Bsw) = b0;
        *(uint4*)(Bsw + 8) = b1;
        __syncthreads();
        bf16x8 af[4], bf[4];
#pragma unroll
        for (int mi = 0; mi < 4; mi++)
            af[mi] = *(const bf16x8*)(As + (wm * 64 + mi * 16 + l15) * GLD + quad * 8);
#pragma unroll
        for (int ni = 0; ni < 4; ni++)
            bf[ni] = *(const bf16x8*)(Bs + (wn * 64 + ni * 16 + l15) * GLD + quad * 8);
#pragma unroll
        for (int mi = 0; mi < 4; mi++)
#pragma unroll
            for (int ni = 0; ni < 4; ni++)
                acc[mi][ni] = __builtin_amdgcn_mfma_f32_16x16x32_bf16(af[mi], bf[ni], acc[mi][ni], 0, 0, 0);
    }

#pragma unroll
    for (int mi = 0; mi < 4; mi++)
#pragma unroll
        for (int ni = 0; ni < 4; ni++) {
            int n = N0 + wn * 64 + ni * 16 + l15;
            float bias_n = bias[n];
            float vals[4];
#pragma unroll
            for (int r = 0; r < 4; r++)
                vals[r] = acc[mi][ni][r] + bias_n;
            int m0 = M0 + wm * 64 + mi * 16 + quad * 4;
            if (MODE == 0) {
                int b = m0 >> 11, t = m0 & 2047;
                int h = n >> 6, hd = n & 63;
#pragma unroll
                for (int r = 0; r < 4; r++)
                    obf[((size_t)((b * 16 + h) * 2048 + (t + r)) << 6) + hd] = f2b(vals[r]);
                if (vtout) {  // also emit V^T: [bh*64+hd][t], t fast => packed b64
                    *(uint2*)(vtout + ((size_t)((b * 16 + h) * 64 + hd)) * 2048 + t) =
                        make_uint2(pack2(vals[0], vals[1]), pack2(vals[2], vals[3]));
                }
            } else {
#pragma unroll
                for (int r = 0; r < 4; r++)
                    ofp[(size_t)(m0 + r) * 1024 + n] = vals[r];
            }
        }
}

__global__ __launch_bounds__(256) void gemm_qkv_kernel(
    const u16* __restrict__ xb,
    const u16* __restrict__ Wq, const u16* __restrict__ Wk, const u16* __restrict__ Wv,
    const float* __restrict__ bq, const float* __restrict__ bk, const float* __restrict__ bv,
    u16* __restrict__ q, u16* __restrict__ k, u16* __restrict__ v, u16* __restrict__ vT)
{
    const u16* W; const float* bias; u16* o; u16* vt = nullptr;
    if (blockIdx.z == 0)      { W = Wq; bias = bq; o = q; }
    else if (blockIdx.z == 1) { W = Wk; bias = bk; o = k; }
    else                      { W = Wv; bias = bv; o = v; vt = vT; }
    gemm_core<0>(xb, W, bias, o, vt, nullptr);
}

__global__ __launch_bounds__(256) void gemm_out_kernel(
    const u16* __restrict__ ao, const u16* __restrict__ Wo, const float* __restrict__ bo,
    float* __restrict__ out)
{
    gemm_core<1>(ao, Wo, bo, nullptr, nullptr, out);
}

// ---------------- build extended q/k rows (96 dims), temp folded into qe ----------------
__global__ void build_ext_kernel(
    const u16* __restrict__ q, const u16* __restrict__ k, const u16* __restrict__ v,
    const float* __restrict__ Wqs, const float* __restrict__ bqs,
    const float* __restrict__ Wks, const float* __restrict__ bks,
    const float* __restrict__ Wvs, const float* __restrict__ bvs,
    const float* __restrict__ temp_p,
    u16* __restrict__ qe, u16* __restrict__ ke)
{
    int row = blockIdx.x * blockDim.x + threadIdx.x;
    if (row >= 2 * 16 * 2048) return;
    const float temp = *temp_p;
    const u16* qr = q + (size_t)row * 64;
    const u16* kr = k + (size_t)row * 64;
    const u16* vr = v + (size_t)row * 64;

    float qs0 = bqs[0], qs1 = bqs[1], qs2 = bqs[2];
    float ks0 = bks[0], ks1 = bks[1], ks2 = bks[2];
    float vs0 = bvs[0], vs1 = bvs[1], vs2 = bvs[2];
#pragma unroll
    for (int j = 0; j < 64; j += 8) {
        bf16x8 qv = *(const bf16x8*)(qr + j);
        bf16x8 kv = *(const bf16x8*)(kr + j);
        bf16x8 vv = *(const bf16x8*)(vr + j);
#pragma unroll
        for (int i = 0; i < 8; i++) {
            float qf = b2f((u16)qv[i]);
            float kf = b2f((u16)kv[i]);
            float vf = b2f((u16)vv[i]);
            qs0 += qf * Wqs[j + i]; qs1 += qf * Wqs[64 + j + i]; qs2 += qf * Wqs[128 + j + i];
            ks0 += kf * Wks[j + i]; ks1 += kf * Wks[64 + j + i]; ks2 += kf * Wks[128 + j + i];
            vs0 += vf * Wvs[j + i]; vs1 += vf * Wvs[64 + j + i]; vs2 += vf * Wvs[128 + j + i];
        }
    }
    float c0 = ks1 * vs2 - ks2 * vs1;
    float c1 = ks2 * vs0 - ks0 * vs2;
    float c2 = ks0 * vs1 - ks1 * vs0;

    u16* qer = qe + (size_t)row * 96;
    u16* ker = ke + (size_t)row * 96;
#pragma unroll
    for (int j = 0; j < 64; j += 8) {
        bf16x8 qv = *(const bf16x8*)(qr + j);
        bf16x8 sq;
#pragma unroll
        for (int i = 0; i < 8; i++) sq[i] = (short)f2b(b2f((u16)qv[i]) * temp);
        *(bf16x8*)(qer + j) = sq;
        *(bf16x8*)(ker + j) = *(const bf16x8*)(kr + j);
    }
    *(uint2*)(qer + 64) = make_uint2(pack2(qs0 * temp, qs1 * temp), (u32)f2b(qs2 * temp));
    *(uint2*)(ker + 64) = make_uint2(pack2(c0, c1), (u32)f2b(c2));
    uint2 z = make_uint2(0u, 0u);
#pragma unroll
    for (int j = 68; j < 96; j += 4) {
        *(uint2*)(qer + j) = z;
        *(uint2*)(ker + j) = z;
    }
}

// ---------------- flash attention: S computed transposed, XOR-swizzled b128 LDS ----------------
// Ks: [key 0..63][dim chunks, 16 x 16B row, 12 used]   16 KB
// Vt: [d 0..63][key chunks, 8 x 16B row]                8 KB
// Ps: [q 0..127][key chunks, 8 x 16B row]              16 KB  (wave-private rows, no barrier)
__global__ __launch_bounds__(256) void attn_kernel(
    const u16* __restrict__ qe, const u16* __restrict__ ke, const u16* __restrict__ vT,
    u16* __restrict__ out)
{
    __shared__ u16 Ks[64 * 128];
    __shared__ u16 Vt[64 * 64];
    __shared__ u16 Ps[128 * 64];

    const int tid = threadIdx.x;
    const int lane = tid & 63, w = tid >> 6;
    const int l15 = lane & 15, quad = lane >> 4;
    const int lsw = l15 & 7;               // row-based XOR swizzle key for frag reads
    const int bh = blockIdx.y;
    const int q0 = blockIdx.x * 128;

    const u16* qeb = qe + (size_t)bh * 2048 * 96;
    const u16* keb = ke + (size_t)bh * 2048 * 96;
    const u16* vTb = vT + (size_t)bh * 64 * 2048;

    // Q as B-fragments (n = l15 = q within subtile, k = quad*8+j), temp pre-folded
    bf16x8 bq[2][3];
#pragma unroll
    for (int s = 0; s < 2; s++) {
        const u16* qrow = qeb + (size_t)(q0 + w * 32 + s * 16 + l15) * 96;
#pragma unroll
        for (int ks = 0; ks < 3; ks++) bq[s][ks] = *(const bf16x8*)(qrow + ks * 32 + quad * 8);
    }

    f32x4 O[2][4];
    float m_i[2], l_i[2];
#pragma unroll
    for (int s = 0; s < 2; s++) {
        m_i[s] = -1e30f; l_i[s] = 0.f;
#pragma unroll
        for (int dt = 0; dt < 4; dt++) O[s][dt] = (f32x4){0.f, 0.f, 0.f, 0.f};
    }

    const int srow = tid >> 2, spart = tid & 3;  // staging: 4 threads per row
    const int sh = srow & 7;
    u16* Pw[2];
#pragma unroll
    for (int s = 0; s < 2; s++) Pw[s] = Ps + (size_t)(w * 32 + s * 16 + l15) * 64;

    for (int kb = 0; kb < 2048; kb += 64) {
        const u16* kg = keb + (size_t)(kb + srow) * 96;
        uint4 kx0 = *(const uint4*)(kg + spart * 8);
        uint4 kx1 = *(const uint4*)(kg + (spart + 4) * 8);
        uint4 kx2 = *(const uint4*)(kg + (spart + 8) * 8);
        const u16* vg = vTb + (size_t)srow * 2048 + kb;
        uint4 vx0 = *(const uint4*)(vg + spart * 8);
        uint4 vx1 = *(const uint4*)(vg + (spart + 4) * 8);
        __syncthreads();
        *(uint4*)(Ks + srow * 128 + ((spart    ) ^ sh) * 8) = kx0;
        *(uint4*)(Ks + srow * 128 + ((spart + 4) ^ sh) * 8) = kx1;
        *(uint4*)(Ks + srow * 128 + ((spart + 8) ^ sh) * 8) = kx2;
        *(uint4*)(Vt + srow * 64 + ((spart    ) ^ sh) * 8) = vx0;
        *(uint4*)(Vt + srow * 64 + ((spart + 4) ^ sh) * 8) = vx1;
        __syncthreads();

        // ---- St = K * Q^T : rows = keys (A from Ks), cols = q (B from regs) ----
        f32x4 S[2][4];
#pragma unroll
        for (int s = 0; s < 2; s++)
#pragma unroll
            for (int nt = 0; nt < 4; nt++) S[s][nt] = (f32x4){0.f, 0.f, 0.f, 0.f};
#pragma unroll
        for (int ks = 0; ks < 3; ks++) {
            bf16x8 ak[4];
#pragma unroll
            for (int nt = 0; nt < 4; nt++)
                ak[nt] = *(const bf16x8*)(Ks + (nt * 16 + l15) * 128 + ((ks * 4 + quad) ^ lsw) * 8);
#pragma unroll
            for (int s = 0; s < 2; s++)
#pragma unroll
                for (int nt = 0; nt < 4; nt++)
                    S[s][nt] = __builtin_amdgcn_mfma_f32_16x16x32_bf16(ak[nt], bq[s][ks], S[s][nt], 0, 0, 0);
        }

        // ---- lane-local online softmax (lane's column q = l15; 16 keys per lane) ----
#pragma unroll
        for (int s = 0; s < 2; s++) {
            float mx = S[s][0][0];
#pragma unroll
            for (int nt = 0; nt < 4; nt++)
#pragma unroll
                for (int r = 0; r < 4; r++) mx = fmaxf(mx, S[s][nt][r]);
            mx = fmaxf(mx, __shfl_xor(mx, 16));
            mx = fmaxf(mx, __shfl_xor(mx, 32));
            float mnew = fmaxf(m_i[s], mx);
            float alpha = __expf(m_i[s] - mnew);
            m_i[s] = mnew;
            float sum = 0.f;
#pragma unroll
            for (int nt = 0; nt < 4; nt++)
#pragma unroll
                for (int r = 0; r < 4; r++) {
                    float p = __expf(S[s][nt][r] - mnew);
                    S[s][nt][r] = p;
                    sum += p;
                }
            sum += __shfl_xor(sum, 16);
            sum += __shfl_xor(sum, 32);
            l_i[s] = l_i[s] * alpha + sum;
#pragma unroll
            for (int dt = 0; dt < 4; dt++)
#pragma unroll
                for (int r = 0; r < 4; r++) O[s][dt][r] *= alpha;
            // P^T rows: 4 consecutive keys per lane -> packed b64, swizzled chunk
#pragma unroll
            for (int nt = 0; nt < 4; nt++) {
                int c = (nt * 2 + (quad >> 1)) ^ lsw;
                *(uint2*)(Pw[s] + c * 8 + (quad & 1) * 4) =
                    make_uint2(pack2(S[s][nt][0], S[s][nt][1]), pack2(S[s][nt][2], S[s][nt][3]));
            }
        }

        // ---- O^T += V^T * P^T  (A = Vt frags, B = Ps frags; in-wave DS ordering) ----
#pragma unroll
        for (int kk = 0; kk < 2; kk++) {
            bf16x8 av[4];
#pragma unroll
            for (int dt = 0; dt < 4; dt++)
                av[dt] = *(const bf16x8*)(Vt + (dt * 16 + l15) * 64 + ((kk * 4 + quad) ^ lsw) * 8);
#pragma unroll
            for (int s = 0; s < 2; s++) {
                bf16x8 pb = *(const bf16x8*)(Pw[s] + ((kk * 4 + quad) ^ lsw) * 8);
#pragma unroll
                for (int dt = 0; dt < 4; dt++)
                    O[s][dt] = __builtin_amdgcn_mfma_f32_16x16x32_bf16(av[dt], pb, O[s][dt], 0, 0, 0);
            }
        }
    }

    // ---- epilogue: O^T C-layout col=q, rows=4 consecutive d -> packed b64 stores ----
    const int b = bh >> 4, h = bh & 15;
#pragma unroll
    for (int s = 0; s < 2; s++) {
        float linv = 1.0f / l_i[s];
        int tq = q0 + w * 32 + s * 16 + l15;
#pragma unroll
        for (int dt = 0; dt < 4; dt++) {
            int d = h * 64 + dt * 16 + quad * 4;
            *(uint2*)(out + (size_t)(b * 2048 + tq) * 1024 + d) =
                make_uint2(pack2(O[s][dt][0] * linv, O[s][dt][1] * linv),
                           pack2(O[s][dt][2] * linv, O[s][dt][3] * linv));
        }
    }
}

// ---------------- launch ----------------
extern "C" void kernel_launch(void* const* d_in, const int* in_sizes, int n_in,
                              void* d_out, int out_size, void* d_ws, size_t ws_size,
                              hipStream_t stream)
{
    (void)in_sizes; (void)n_in; (void)out_size; (void)ws_size;
    const float* x   = (const float*)d_in[0];
    const float* Wq  = (const float*)d_in[1];
    const float* bq  = (const float*)d_in[2];
    const float* Wk  = (const float*)d_in[3];
    const float* bk  = (const float*)d_in[4];
    const float* Wv  = (const float*)d_in[5];
    const float* bv  = (const float*)d_in[6];
    const float* Wo  = (const float*)d_in[7];
    const float* bo  = (const float*)d_in[8];
    const float* Wqs = (const float*)d_in[9];
    const float* bqs = (const float*)d_in[10];
    const float* Wks = (const float*)d_in[11];
    const float* bks = (const float*)d_in[12];
    const float* Wvs = (const float*)d_in[13];
    const float* bvs = (const float*)d_in[14];
    const float* temp = (const float*)d_in[15];

    char* ws = (char*)d_ws;
    u16* xb  = (u16*)(ws);                 // 8 MB (x bf16; reused as aob after gemm_qkv)
    u16* Wqb = (u16*)(ws + 8388608);       // 2 MB
    u16* Wkb = (u16*)(ws + 10485760);      // 2 MB
    u16* Wvb = (u16*)(ws + 12582912);      // 2 MB
    u16* Wob = (u16*)(ws + 14680064);      // 2 MB
    u16* qb  = (u16*)(ws + 16777216);      // 8 MB  [B,H,T,64]
    u16* kbq = (u16*)(ws + 25165824);      // 8 MB
    u16* vbq = (u16*)(ws + 33554432);      // 8 MB
    u16* qeb = (u16*)(ws + 41943040);      // 12 MB [B,H,T,96]
    u16* keb = (u16*)(ws + 54525952);      // 12 MB
    u16* vTb = (u16*)(ws + 67108864);      // 8 MB  [B,H,64,T]
    u16* aob = xb;                         // alias: xb dead after gemm_qkv

    cast_all_kernel<<<8192, 256, 0, stream>>>(x, Wq, Wk, Wv, Wo, xb, Wqb, Wkb, Wvb, Wob);
    gemm_qkv_kernel<<<dim3(8, 32, 3), 256, 0, stream>>>(xb, Wqb, Wkb, Wvb, bq, bk, bv, qb, kbq, vbq, vTb);
    build_ext_kernel<<<256, 256, 0, stream>>>(qb, kbq, vbq, Wqs, bqs, Wks, bks, Wvs, bvs, temp, qeb, keb);
    attn_kernel<<<dim3(16, 32), 256, 0, stream>>>(qeb, keb, vTb, aob);
    gemm_out_kernel<<<dim3(8, 32), 256, 0, stream>>>(aob, Wob, bo, (float*)d_out);
}